// Round 3
// baseline (1721.179 us; speedup 1.0000x reference)
//
#include <hip/hip_runtime.h>
#include <hip/hip_bf16.h>
#include <stdint.h>

// Problem constants
#define TOKENS 4096
#define DM     512
#define VOCAB  128000
#define BN     256                 // vocab rows per block tile
#define BM     256                 // tokens per block tile
#define BK     64                  // k per staged tile
#define NCHUNK (VOCAB / BN)        // 500
#define NTILE  (TOKENS / BM)       // 16
#define NKC    (DM / BK)           // 8
#define SLOTS_PER_KC 2048          // 16-B fragment slots per (chunk, kc)

typedef __attribute__((ext_vector_type(8)))  short short8;
typedef __attribute__((ext_vector_type(16))) float f32x16;

__device__ __forceinline__ unsigned short f2bf(float f) {
  unsigned u;
  __builtin_memcpy(&u, &f, 4);
  u += 0x7fffu + ((u >> 16) & 1u);        // round-to-nearest-even
  return (unsigned short)(u >> 16);
}

__device__ __forceinline__ uint4 pack8(float4 v0, float4 v1) {
  ushort a0 = f2bf(v0.x), a1 = f2bf(v0.y), a2 = f2bf(v0.z), a3 = f2bf(v0.w);
  ushort a4 = f2bf(v1.x), a5 = f2bf(v1.y), a6 = f2bf(v1.z), a7 = f2bf(v1.w);
  uint4 r;
  r.x = (unsigned)a0 | ((unsigned)a1 << 16);
  r.y = (unsigned)a2 | ((unsigned)a3 << 16);
  r.z = (unsigned)a4 | ((unsigned)a5 << 16);
  r.w = (unsigned)a6 | ((unsigned)a7 << 16);
  return r;
}

// ------ stage 0: fp32 -> bf16 in MFMA-fragment order ------------------------
// slot(row-chunk cn|ct, kc, ig, ks, lane) holds M[chunk*256+ig*32+(lane&31)]
//                                        [kc*64+ks*16+(lane>>5)*8 .. +8)
// linear slot index = (chunk*8+kc)*2048 + (ig*4+ks)*64 + lane   (16 B units)
__global__ void cvt_w_swz(const float* __restrict__ w, uint4* __restrict__ ws) {
  size_t s = (size_t)blockIdx.x * 256 + threadIdx.x;   // 8-elem group id
  int row = (int)(s >> 6);
  int g   = (int)(s & 63);
  const float* p = w + (size_t)row * DM + g * 8;
  uint4 o = pack8(*(const float4*)p, *(const float4*)(p + 4));
  int cn = row >> 8, ig = (row >> 5) & 7, rl = row & 31;
  int kc = g >> 3, ks = (g >> 1) & 3, half = g & 1;
  ws[(size_t)(cn * 8 + kc) * SLOTS_PER_KC + (ig * 4 + ks) * 64 + half * 32 + rl] = o;
}

__global__ void cvt_x_swz(const float* __restrict__ x, uint4* __restrict__ xs,
                          float* __restrict__ out) {
  size_t s = (size_t)blockIdx.x * 256 + threadIdx.x;
  int row = (int)(s >> 6);
  int g   = (int)(s & 63);
  const float* p = x + (size_t)row * DM + g * 8;
  uint4 o = pack8(*(const float4*)p, *(const float4*)(p + 4));
  int ct = row >> 8, jg = (row >> 5) & 7, rl = row & 31;
  int kc = g >> 3, ks = (g >> 1) & 3, half = g & 1;
  xs[(size_t)(ct * 8 + kc) * SLOTS_PER_KC + (jg * 4 + ks) * 64 + half * 32 + rl] = o;
  if (blockIdx.x == 0 && threadIdx.x == 0) out[0] = 0.0f;
}

// ------ stage 1: GEMM + per-chunk sumexp ------------------------------------
// 256 thr = 4 waves, wave tile 128x128 (4x4 grid of 32x32x16 MFMA).
// A (W): double-buffered LDS, coalesced global_load_lds from swizzled wb.
// B (x): direct coalesced global loads from swizzled xb (L2-hot, 4 MB).
template <bool SWZ>
__global__ __launch_bounds__(256, 1) void gemm_kernel(
    const void* __restrict__ Wp, const uint4* __restrict__ Xs,
    float* __restrict__ part) {
  extern __shared__ char smem[];          // 2 x 32768 A buffers + 2048 sc
  const int tid  = threadIdx.x;
  const int lane = tid & 63;
  const int wave = tid >> 6;
  const int wn   = wave >> 1;             // vocab half of block tile
  const int wm   = wave & 1;              // token half of block tile
  const int cn   = blockIdx.x >> 4;       // vocab chunk 0..499
  const int ct   = blockIdx.x & 15;       // token tile 0..15

  auto stage = [&](int kc, int bsel) {
    char* buf = smem + bsel * 32768;
    if (SWZ) {
      const uint4* g = (const uint4*)Wp + (size_t)(cn * 8 + kc) * SLOTS_PER_KC + tid;
      #pragma unroll
      for (int u = 0; u < 8; ++u) {
        __builtin_amdgcn_global_load_lds(
            (const __attribute__((address_space(1))) void*)(g + u * 256),
            (__attribute__((address_space(3))) void*)(buf + (u * 256 + wave * 64) * 16),
            16, 0, 0);
      }
    } else {
      const float* W = (const float*)Wp;
      #pragma unroll
      for (int u = 0; u < 8; ++u) {
        int slot = u * 256 + tid;
        int ig = slot >> 8, ks = (slot >> 6) & 3, l = slot & 63;
        const float* p = W + (size_t)(cn * 256 + ig * 32 + (l & 31)) * DM
                           + kc * 64 + ks * 16 + (l >> 5) * 8;
        *(uint4*)(buf + slot * 16) = pack8(*(const float4*)p, *(const float4*)(p + 4));
      }
    }
  };

  // B fragments: slot = (ct*8+kc)*2048 + ((wm*4+j)*4+ks)*64 + lane
  auto load_b = [&](short8 b[2][4], int kc, int ksb) {
    const uint4* base = Xs + (size_t)(ct * 8 + kc) * SLOTS_PER_KC + lane;
    #pragma unroll
    for (int ks = 0; ks < 2; ++ks)
      #pragma unroll
      for (int j = 0; j < 4; ++j) {
        uint4 v = base[((wm * 4 + j) * 4 + ksb + ks) * 64];
        b[ks][j] = *(short8*)&v;
      }
  };

  f32x16 acc[4][4];
  #pragma unroll
  for (int i = 0; i < 4; ++i)
    #pragma unroll
    for (int j = 0; j < 4; ++j)
      #pragma unroll
      for (int r = 0; r < 16; ++r) acc[i][j][r] = 0.f;

  short8 bA[2][4], bB[2][4];
  load_b(bA, 0, 0);
  stage(0, 0);

  #pragma unroll 1
  for (int kc = 0; kc < NKC; ++kc) {
    __syncthreads();                      // DMA(kc) + all prefetches drained
    if (kc < NKC - 1) stage(kc + 1, (kc + 1) & 1);
    load_b(bB, kc, 2);                    // B for ks=2,3 of this kc
    const char* rbuf = smem + (kc & 1) * 32768;
    #pragma unroll
    for (int ks = 0; ks < 2; ++ks) {
      short8 a[4];
      #pragma unroll
      for (int i = 0; i < 4; ++i)
        a[i] = *(const short8*)(rbuf + (((wn * 4 + i) * 4 + ks) << 10) + lane * 16);
      #pragma unroll
      for (int i = 0; i < 4; ++i)
        #pragma unroll
        for (int j = 0; j < 4; ++j)
          acc[i][j] = __builtin_amdgcn_mfma_f32_32x32x16_bf16(
              a[i], bA[ks][j], acc[i][j], 0, 0, 0);
    }
    if (kc < NKC - 1) load_b(bA, kc + 1, 0);  // B for ks=0,1 of next kc
    #pragma unroll
    for (int ks = 0; ks < 2; ++ks) {
      short8 a[4];
      #pragma unroll
      for (int i = 0; i < 4; ++i)
        a[i] = *(const short8*)(rbuf + (((wn * 4 + i) * 4 + 2 + ks) << 10) + lane * 16);
      #pragma unroll
      for (int i = 0; i < 4; ++i)
        #pragma unroll
        for (int j = 0; j < 4; ++j)
          acc[i][j] = __builtin_amdgcn_mfma_f32_32x32x16_bf16(
              a[i], bB[ks][j], acc[i][j], 0, 0, 0);
    }
  }

  // epilogue: token = ct*256 + (wm*4+j)*32 + (lane&31);
  // vocab row = cn*256 + (wn*4+i)*32 + (reg&3)+8*(reg>>2)+4*(lane>>5)
  float* sc = (float*)(smem + 65536);
  #pragma unroll
  for (int j = 0; j < 4; ++j) {
    float s = 0.f;
    #pragma unroll
    for (int i = 0; i < 4; ++i)
      #pragma unroll
      for (int r = 0; r < 16; ++r) s += __expf(acc[i][j][r]);
    s += __shfl_xor(s, 32, 64);           // merge the two row-halves
    if (lane < 32) sc[wn * 256 + (wm * 4 + j) * 32 + (lane & 31)] = s;
  }
  __syncthreads();
  part[(size_t)cn * TOKENS + ct * 256 + tid] = sc[tid] + sc[256 + tid];
}

// ------ stage 2a: exact fp32 target scores ----------------------------------
__global__ void target_dot_kernel(const float* __restrict__ x,
                                  const float* __restrict__ W,
                                  const int* __restrict__ tgt,
                                  float* __restrict__ T) {
  int wave = threadIdx.x >> 6, lane = threadIdx.x & 63;
  int i = blockIdx.x * 4 + wave;
  int r = tgt[i];
  const float4* xp = (const float4*)(x + (size_t)i * DM + lane * 8);
  const float4* wp = (const float4*)(W + (size_t)r * DM + lane * 8);
  float4 a0 = xp[0], a1 = xp[1], b0 = wp[0], b1 = wp[1];
  float s = a0.x * b0.x + a0.y * b0.y + a0.z * b0.z + a0.w * b0.w
          + a1.x * b1.x + a1.y * b1.y + a1.z * b1.z + a1.w * b1.w;
  #pragma unroll
  for (int m = 32; m >= 1; m >>= 1) s += __shfl_xor(s, m, 64);
  if (lane == 0) T[i] = s;
}

// ------ stage 2b: reduce chunks, loss, total --------------------------------
__global__ void reduce_loss_kernel(const float* __restrict__ part,
                                   const float* __restrict__ T,
                                   float* __restrict__ out) {
  __shared__ float red[256];
  int tid = threadIdx.x;
  int tok = blockIdx.x * 64 + (tid & 63);
  int g = tid >> 6;
  float S = 0.f;
  for (int cc = g; cc < NCHUNK; cc += 4) S += part[(size_t)cc * TOKENS + tok];
  red[tid] = S;
  __syncthreads();
  if (tid < 64) {
    float Sa = red[tid] + red[64 + tid] + red[128 + tid] + red[192 + tid];
    float loss = __logf(Sa) - T[tok];     // max-free form (|logit| < ~5)
    #pragma unroll
    for (int m = 32; m >= 1; m >>= 1) loss += __shfl_xor(loss, m, 64);
    if (tid == 0) atomicAdd(out, loss);
  }
}

extern "C" void kernel_launch(void* const* d_in, const int* in_sizes, int n_in,
                              void* d_out, int out_size, void* d_ws, size_t ws_size,
                              hipStream_t stream) {
  const float* x   = (const float*)d_in[0];
  const float* W   = (const float*)d_in[1];
  const int*   tgt = (const int*)d_in[2];
  float* out = (float*)d_out;

  const size_t XS_SZ   = (size_t)TOKENS * DM * 2;        // 4,194,304 (swizzled bf16 x)
  const size_t WS_SZ   = (size_t)VOCAB * DM * 2;         // 131,072,000 (swizzled bf16 W)
  const size_t PART_SZ = (size_t)NCHUNK * TOKENS * 4;    // 8,192,000
  const size_t T_SZ    = (size_t)TOKENS * 4;
  const bool fast = ws_size >= XS_SZ + WS_SZ + PART_SZ + T_SZ;   // ~143.5 MB

  uint4* xs   = (uint4*)d_ws;
  uint4* wsw  = (uint4*)((char*)d_ws + XS_SZ);
  float* part = (float*)((char*)d_ws + XS_SZ + (fast ? WS_SZ : 0));
  float* T    = (float*)((char*)part + PART_SZ);

  const int LDS_BYTES = 65536 + 2048;

  cvt_x_swz<<<TOKENS * (DM / 8) / 256, 256, 0, stream>>>(x, xs, out);

  if (fast) {
    cvt_w_swz<<<(int)((size_t)VOCAB * (DM / 8) / 256), 256, 0, stream>>>(W, wsw);
    hipFuncSetAttribute(reinterpret_cast<const void*>(gemm_kernel<true>),
                        hipFuncAttributeMaxDynamicSharedMemorySize, LDS_BYTES);
    gemm_kernel<true><<<NCHUNK * NTILE, 256, LDS_BYTES, stream>>>(wsw, xs, part);
  } else {
    hipFuncSetAttribute(reinterpret_cast<const void*>(gemm_kernel<false>),
                        hipFuncAttributeMaxDynamicSharedMemorySize, LDS_BYTES);
    gemm_kernel<false><<<NCHUNK * NTILE, 256, LDS_BYTES, stream>>>(W, xs, part);
  }

  target_dot_kernel<<<TOKENS / 4, 256, 0, stream>>>(x, W, tgt, T);
  reduce_loss_kernel<<<TOKENS / 64, 256, 0, stream>>>(part, T, out);
}